// Round 7
// baseline (169.499 us; speedup 1.0000x reference)
//
#include <hip/hip_runtime.h>

// DenseFeatureNumericEmbedding: out[b, f*16+e] = sum_h relu(x[b,f]*W1[f,h]+b1[f,h])*W2[f,e,h] + b2[f,e]
// Piecewise-linear-in-x reformulation: per (f,e), the map x -> emb is piecewise linear
// with breakpoints t_h = -b1/W1. Precompute slope/intercept tables per (f, interval, e),
// then the main kernel is: digitize x + 4 FMA + one coalesced 16B store per thread.
//
// R1: lane remap (eq,fl,row) -> contiguous 256B store segments, nontemporal stores.
// R3: register-resident digitize (count k = #{t_i <= x}, pure VALU, no LDS search).
// R5: (a) build_tables parallelized over (f,e) [-25us, confirmed]; (b) embed LDS-free
//     [neutral!]; (c) digitize split across eq-lanes.
// R8 analysis: timed region = harness 512MiB poison-fill (~85us) + build (~4us) +
//     embed (~75us). Embed was IDENTICAL with and without LDS staging -> not
//     table-read-bound. 134MB nt-store stream at only ~1.8 TB/s vs fill's 6.2.
//     Cause: x-major grid put ~1024 co-resident blocks on ALL batch rows x few
//     feature-groups -> HBM sees sparse 256B fragments strided 8KB over the whole
//     134MB extent (row-buffer thrash). R8 change: SWAP GRID DIMS. Co-resident
//     blocks now = all 32 feature-groups x consecutive batch chunks -> dense
//     contiguous ~32MB write window sweeping forward (fill-like stream), and x rows
//     get perfect L2 reuse across the 32 f-group blocks of a chunk.

#define F_   128
#define H_   64
#define E_   16
#define NROW 65            // intervals 0..64
#define GRS  32            // global table row stride (16 S + 16 T floats)
#define FPB  4             // features per block
#define RPI  16            // batch rows per iteration (256 threads / 16 lanes-per-row)
#define ITERS 8
#define BPB  (RPI * ITERS) // 128 batch rows per block
#define THREADS 256

typedef float vf4 __attribute__((ext_vector_type(4)));   // native vector for nt-store

// ---------------- build kernel: one wave per (feature, e) ----------------
__global__ __launch_bounds__(64) void build_tables(
    const float* __restrict__ W1, const float* __restrict__ B1,
    const float* __restrict__ W2, const float* __restrict__ B2,
    float* __restrict__ tbl, float* __restrict__ bps)
{
    const int f = blockIdx.x;   // 0..127
    const int e = blockIdx.y;   // 0..15
    const int h = threadIdx.x;  // 0..63

    __shared__ float ts_raw[H_];
    __shared__ float ts_sorted[H_];
    __shared__ float scS[H_];
    __shared__ float scT[H_];

    const float w1 = W1[f * H_ + h];
    const float bb = B1[f * H_ + h];
    const bool  slope = (w1 != 0.0f);
    const float t   = slope ? (-bb / w1) : __builtin_inff();
    const float sgn = slope ? (w1 > 0.0f ? 1.0f : -1.0f) : 0.0f;
    // active as x -> -inf: W1<0 terms (x*W1 -> +inf), plus constant-on terms (W1==0, b1>0)
    const bool act0 = (w1 < 0.0f) || (!slope && bb > 0.0f);

    ts_raw[h] = t;
    __syncthreads();
    int rank = 0;
    #pragma unroll
    for (int j = 0; j < H_; ++j) {
        float tj = ts_raw[j];
        rank += (tj < t || (tj == t && j < h)) ? 1 : 0;  // tie-break by index -> permutation
    }
    ts_sorted[rank] = t;
    __syncthreads();
    if (e == 0) bps[f * H_ + h] = ts_sorted[h];

    const float w2 = W2[(f * E_ + e) * H_ + h];
    // crossing t_h upward: W1>0 -> term turns ON (+), W1<0 -> OFF (-)
    const float dS = sgn * w1 * w2;
    const float dT = sgn * bb * w2;
    float bS = act0 ? w1 * w2 : 0.0f;
    float bT = act0 ? bb * w2 : 0.0f;
    #pragma unroll
    for (int d = 32; d; d >>= 1) { bS += __shfl_xor(bS, d); bT += __shfl_xor(bT, d); }

    scS[rank] = dS; scT[rank] = dT;  // scatter deltas into sorted order
    __syncthreads();
    float vS = scS[h], vT = scT[h];
    #pragma unroll
    for (int d = 1; d < 64; d <<= 1) {   // inclusive scan over sorted positions
        float uS = __shfl_up(vS, (unsigned)d);
        float uT = __shfl_up(vT, (unsigned)d);
        if (h >= d) { vS += uS; vT += uT; }
    }
    const float b2v = B2[f * E_ + e];
    float* row = tbl + ((size_t)f * NROW + (h + 1)) * GRS;  // interval k = h+1
    row[e]      = bS + vS;
    row[E_ + e] = bT + vT + b2v;
    if (h == 0) {
        float* r0 = tbl + (size_t)f * NROW * GRS;           // interval 0
        r0[e]      = bS;
        r0[E_ + e] = bT + b2v;
    }
}

// ---------------- main kernel (no LDS) ----------------
// lane map: eq = tid&3 (e-quartet), fl = (tid>>2)&3 (feature of 4), rloc = tid>>4 (0..15)
// store addr = out + b*2048 + (f0+fl)*16 + eq*4  -> lanes 0..15 cover 256B contiguous.
// R8: blockIdx.x = feature-group (32), blockIdx.y = batch-chunk (128). x-major dispatch
// makes the ~1024 co-resident blocks cover a DENSE contiguous batch window (all
// features of consecutive rows) -> sequential HBM write stream + L2-shared x rows.
__global__ __launch_bounds__(THREADS, 4) void embed_main(
    const float* __restrict__ x, const float* __restrict__ tbl,
    const float* __restrict__ bps, float* __restrict__ out)
{
    const int tid = threadIdx.x;
    const int f0  = blockIdx.x * FPB;

    const int   eq   = tid & 3;
    const int   fl   = (tid >> 2) & 3;
    const int   rloc = tid >> 4;          // 0..15
    const int   f    = f0 + fl;
    const int bbase  = blockIdx.y * BPB;

    // x gather, issued first (eq-lanes share the address -> one merged request)
    float xs[ITERS];
    #pragma unroll
    for (int it = 0; it < ITERS; ++it)
        xs[it] = x[(size_t)(bbase + it * RPI + rloc) * F_ + f];

    // this lane's 16 of the 64 sorted breakpoints (digitize split across eq-lanes)
    float4 bp[4];
    #pragma unroll
    for (int i = 0; i < 4; ++i)
        bp[i] = *(const float4*)(bps + (size_t)f * H_ + eq * 16 + 4 * i);

    const float* ftbl = tbl + (size_t)f * NROW * GRS;

    #pragma unroll
    for (int it = 0; it < ITERS; ++it) {
        const int   b  = bbase + it * RPI + rloc;
        const float xv = xs[it];
        // partial count of breakpoints <= xv (16 per eq-lane), pure VALU
        int c = 0;
        #pragma unroll
        for (int i = 0; i < 4; ++i) {
            c += (bp[i].x <= xv) ? 1 : 0;
            c += (bp[i].y <= xv) ? 1 : 0;
            c += (bp[i].z <= xv) ? 1 : 0;
            c += (bp[i].w <= xv) ? 1 : 0;
        }
        // combine across the 4 eq-lanes (they share xv): k in [0,64], same in all 4
        c += __shfl_xor(c, 1);
        c += __shfl_xor(c, 2);
        // direct L2 read of the interval row: eq-lanes cover full 64B lines
        const float* row = ftbl + (size_t)c * GRS + eq * 4;
        float4 S = *(const float4*)(row);
        float4 T = *(const float4*)(row + E_);
        vf4 o;
        o.x = fmaf(S.x, xv, T.x);
        o.y = fmaf(S.y, xv, T.y);
        o.z = fmaf(S.z, xv, T.z);
        o.w = fmaf(S.w, xv, T.w);
        vf4* op = (vf4*)(out + (size_t)b * (F_ * E_) + f * E_ + eq * 4);
        __builtin_nontemporal_store(o, op);
    }
}

extern "C" void kernel_launch(void* const* d_in, const int* in_sizes, int n_in,
                              void* d_out, int out_size, void* d_ws, size_t ws_size,
                              hipStream_t stream) {
    const float* x  = (const float*)d_in[0];
    const float* W1 = (const float*)d_in[1];
    const float* b1 = (const float*)d_in[2];
    const float* W2 = (const float*)d_in[3];
    const float* b2 = (const float*)d_in[4];
    float* out = (float*)d_out;
    const int B = in_sizes[0] / F_;     // 16384

    // workspace: table 128*65*32 floats (1.02 MB) + sorted breakpoints 128*64 floats (32 KB)
    float* tbl = (float*)d_ws;
    float* bps = tbl + (size_t)F_ * NROW * GRS;

    build_tables<<<dim3(F_, E_), 64, 0, stream>>>(W1, b1, W2, b2, tbl, bps);
    dim3 grid(F_ / FPB, B / BPB);       // (32, 128): x-major -> dense batch window resident
    embed_main<<<grid, THREADS, 0, stream>>>(x, tbl, bps, out);
}

// Round 8
// 165.543 us; speedup vs baseline: 1.0239x; 1.0239x over previous
//
#include <hip/hip_runtime.h>

// DenseFeatureNumericEmbedding: out[b, f*16+e] = sum_h relu(x[b,f]*W1[f,h]+b1[f,h])*W2[f,e,h] + b2[f,e]
// Piecewise-linear-in-x reformulation: per (f,e), the map x -> emb is piecewise linear
// with breakpoints t_h = -b1/W1. Precompute slope/intercept tables per (f, interval, e),
// then the main kernel is: digitize x + 4 FMA + one coalesced 16B store per thread.
//
// R1: lane remap (eq,fl,row) -> contiguous 256B store segments.
// R3: register-resident digitize (count k = #{t_i <= x}, pure VALU, no LDS search).
// R5: (a) build_tables parallelized over (f,e) [-25us, confirmed]; (b) embed LDS-free
//     [neutral]; (c) digitize split across eq-lanes.
// R8: grid dim swap for dense write window [NEUTRAL -> DRAM-page-locality theory dead].
// R9 theory: embed (~78us) is pinned at 1.7 TB/s writes vs the harness fill's 6.4 TB/s
//     plain-store stream, and is insensitive to read path (R5b) and write locality (R8).
//     Remaining constant: the NONTEMPORAL store flag. nt bypasses L2 allocation, so the
//     4x256B scattered wave-fragments are not write-combined and hit HBM as sub-burst
//     sector writes (~3x loss). Our fragments are full aligned 128B lines -> plain
//     stores write-combine in L2 with no RMW, and stream out at fill rate.
//     R9 change (single variable): drop __builtin_nontemporal_store -> plain store.

#define F_   128
#define H_   64
#define E_   16
#define NROW 65            // intervals 0..64
#define GRS  32            // global table row stride (16 S + 16 T floats)
#define FPB  4             // features per block
#define RPI  16            // batch rows per iteration (256 threads / 16 lanes-per-row)
#define ITERS 8
#define BPB  (RPI * ITERS) // 128 batch rows per block
#define THREADS 256

typedef float vf4 __attribute__((ext_vector_type(4)));

// ---------------- build kernel: one wave per (feature, e) ----------------
__global__ __launch_bounds__(64) void build_tables(
    const float* __restrict__ W1, const float* __restrict__ B1,
    const float* __restrict__ W2, const float* __restrict__ B2,
    float* __restrict__ tbl, float* __restrict__ bps)
{
    const int f = blockIdx.x;   // 0..127
    const int e = blockIdx.y;   // 0..15
    const int h = threadIdx.x;  // 0..63

    __shared__ float ts_raw[H_];
    __shared__ float ts_sorted[H_];
    __shared__ float scS[H_];
    __shared__ float scT[H_];

    const float w1 = W1[f * H_ + h];
    const float bb = B1[f * H_ + h];
    const bool  slope = (w1 != 0.0f);
    const float t   = slope ? (-bb / w1) : __builtin_inff();
    const float sgn = slope ? (w1 > 0.0f ? 1.0f : -1.0f) : 0.0f;
    // active as x -> -inf: W1<0 terms (x*W1 -> +inf), plus constant-on terms (W1==0, b1>0)
    const bool act0 = (w1 < 0.0f) || (!slope && bb > 0.0f);

    ts_raw[h] = t;
    __syncthreads();
    int rank = 0;
    #pragma unroll
    for (int j = 0; j < H_; ++j) {
        float tj = ts_raw[j];
        rank += (tj < t || (tj == t && j < h)) ? 1 : 0;  // tie-break by index -> permutation
    }
    ts_sorted[rank] = t;
    __syncthreads();
    if (e == 0) bps[f * H_ + h] = ts_sorted[h];

    const float w2 = W2[(f * E_ + e) * H_ + h];
    // crossing t_h upward: W1>0 -> term turns ON (+), W1<0 -> OFF (-)
    const float dS = sgn * w1 * w2;
    const float dT = sgn * bb * w2;
    float bS = act0 ? w1 * w2 : 0.0f;
    float bT = act0 ? bb * w2 : 0.0f;
    #pragma unroll
    for (int d = 32; d; d >>= 1) { bS += __shfl_xor(bS, d); bT += __shfl_xor(bT, d); }

    scS[rank] = dS; scT[rank] = dT;  // scatter deltas into sorted order
    __syncthreads();
    float vS = scS[h], vT = scT[h];
    #pragma unroll
    for (int d = 1; d < 64; d <<= 1) {   // inclusive scan over sorted positions
        float uS = __shfl_up(vS, (unsigned)d);
        float uT = __shfl_up(vT, (unsigned)d);
        if (h >= d) { vS += uS; vT += uT; }
    }
    const float b2v = B2[f * E_ + e];
    float* row = tbl + ((size_t)f * NROW + (h + 1)) * GRS;  // interval k = h+1
    row[e]      = bS + vS;
    row[E_ + e] = bT + vT + b2v;
    if (h == 0) {
        float* r0 = tbl + (size_t)f * NROW * GRS;           // interval 0
        r0[e]      = bS;
        r0[E_ + e] = bT + b2v;
    }
}

// ---------------- main kernel (no LDS) ----------------
// lane map: eq = tid&3 (e-quartet), fl = (tid>>2)&3 (feature of 4), rloc = tid>>4 (0..15)
// store addr = out + b*2048 + (f0+fl)*16 + eq*4  -> lanes 0..15 cover 256B contiguous.
__global__ __launch_bounds__(THREADS, 4) void embed_main(
    const float* __restrict__ x, const float* __restrict__ tbl,
    const float* __restrict__ bps, float* __restrict__ out)
{
    const int tid = threadIdx.x;
    const int f0  = blockIdx.x * FPB;

    const int   eq   = tid & 3;
    const int   fl   = (tid >> 2) & 3;
    const int   rloc = tid >> 4;          // 0..15
    const int   f    = f0 + fl;
    const int bbase  = blockIdx.y * BPB;

    // x gather, issued first (eq-lanes share the address -> one merged request)
    float xs[ITERS];
    #pragma unroll
    for (int it = 0; it < ITERS; ++it)
        xs[it] = x[(size_t)(bbase + it * RPI + rloc) * F_ + f];

    // this lane's 16 of the 64 sorted breakpoints (digitize split across eq-lanes)
    float4 bp[4];
    #pragma unroll
    for (int i = 0; i < 4; ++i)
        bp[i] = *(const float4*)(bps + (size_t)f * H_ + eq * 16 + 4 * i);

    const float* ftbl = tbl + (size_t)f * NROW * GRS;

    #pragma unroll
    for (int it = 0; it < ITERS; ++it) {
        const int   b  = bbase + it * RPI + rloc;
        const float xv = xs[it];
        // partial count of breakpoints <= xv (16 per eq-lane), pure VALU
        int c = 0;
        #pragma unroll
        for (int i = 0; i < 4; ++i) {
            c += (bp[i].x <= xv) ? 1 : 0;
            c += (bp[i].y <= xv) ? 1 : 0;
            c += (bp[i].z <= xv) ? 1 : 0;
            c += (bp[i].w <= xv) ? 1 : 0;
        }
        // combine across the 4 eq-lanes (they share xv): k in [0,64], same in all 4
        c += __shfl_xor(c, 1);
        c += __shfl_xor(c, 2);
        // direct L2 read of the interval row: eq-lanes cover full 64B lines
        const float* row = ftbl + (size_t)c * GRS + eq * 4;
        float4 S = *(const float4*)(row);
        float4 T = *(const float4*)(row + E_);
        vf4 o;
        o.x = fmaf(S.x, xv, T.x);
        o.y = fmaf(S.y, xv, T.y);
        o.z = fmaf(S.z, xv, T.z);
        o.w = fmaf(S.w, xv, T.w);
        // R9: plain store (was nontemporal). Full aligned 128B lines -> L2
        // write-combines and streams at fill rate; no RMW.
        vf4* op = (vf4*)(out + (size_t)b * (F_ * E_) + f * E_ + eq * 4);
        *op = o;
    }
}

extern "C" void kernel_launch(void* const* d_in, const int* in_sizes, int n_in,
                              void* d_out, int out_size, void* d_ws, size_t ws_size,
                              hipStream_t stream) {
    const float* x  = (const float*)d_in[0];
    const float* W1 = (const float*)d_in[1];
    const float* b1 = (const float*)d_in[2];
    const float* W2 = (const float*)d_in[3];
    const float* b2 = (const float*)d_in[4];
    float* out = (float*)d_out;
    const int B = in_sizes[0] / F_;     // 16384

    // workspace: table 128*65*32 floats (1.02 MB) + sorted breakpoints 128*64 floats (32 KB)
    float* tbl = (float*)d_ws;
    float* bps = tbl + (size_t)F_ * NROW * GRS;

    build_tables<<<dim3(F_, E_), 64, 0, stream>>>(W1, b1, W2, b2, tbl, bps);
    dim3 grid(F_ / FPB, B / BPB);       // (32, 128): x-major -> dense batch window resident
    embed_main<<<grid, THREADS, 0, stream>>>(x, tbl, bps, out);
}